// Round 3
// baseline (745.178 us; speedup 1.0000x reference)
//
#include <hip/hip_runtime.h>
#include <stdint.h>
#include <stddef.h>

typedef __attribute__((ext_vector_type(8)))  _Float16 f16x8;
typedef __attribute__((ext_vector_type(16))) float    f32x16;
typedef __attribute__((ext_vector_type(4)))  float    f32x4;
typedef __attribute__((ext_vector_type(4)))  unsigned int u32x4;

#define B_ 4
#define L_ 8192
#define D_ 1024
#define BL 32768
#define XROWS 32769              // 1 pad row + 32768
#define XCV_BYTES (256u * XROWS * 16u)   // 134,221,824
#define WCV_BYTES (256u * 1024u * 16u)   //   4,194,304
#define BUFSZ 65792u             // 8*4128 (x) + 2*16384 (Wq,Wk) per LDS buffer

__device__ __forceinline__ void gload16(const void* g, void* l){
  __builtin_amdgcn_global_load_lds((const __attribute__((address_space(1))) void*)g,
                                   (__attribute__((address_space(3))) void*)l, 16, 0, 0);
}

// ---------------------------------------------------------------------------
// K0: convert f32 [nrows][1024] into packed f16 hi/lo planes.
// Plane p = ks*8 + c (ks = 32-k step, c<4: hi of k_local=c*8.., c>=4: lo).
// Plane entry = one row (16 B = 8 f16). One merged launch converts x, Wq, Wk.
// ---------------------------------------------------------------------------
__global__ void k0_cvt(const float* __restrict__ x, const float* __restrict__ Wq,
                       const float* __restrict__ Wk, unsigned char* __restrict__ xcv)
{
  __shared__ unsigned short hi[64][128];
  __shared__ unsigned short lo[64][128];
  const int bx = blockIdx.x, kt = blockIdx.y, tid = threadIdx.x;
  const float* src; unsigned char* dst; int rowstride, pad, rt;
  if (bx < 512){ src = x;  dst = xcv;                         rowstride = XROWS; pad = 1; rt = bx; }
  else if (bx < 528){ src = Wq; dst = xcv + XCV_BYTES;        rowstride = 1024;  pad = 0; rt = bx - 512; }
  else { src = Wk; dst = xcv + XCV_BYTES + WCV_BYTES;         rowstride = 1024;  pad = 0; rt = bx - 528; }

  #pragma unroll
  for (int it = 0; it < 8; ++it){
    int idx = it*256 + tid;          // 2048 f32x4 loads (64 rows x 128 k)
    int r = idx >> 5, q4 = idx & 31;
    f32x4 v = *(const f32x4*)(src + (size_t)(rt*64 + r)*1024 + kt*128 + q4*4);
    #pragma unroll
    for (int j = 0; j < 4; ++j){
      float f = v[j];
      _Float16 h = (_Float16)f;
      _Float16 l = (_Float16)(f - (float)h);
      hi[r][q4*4+j] = __builtin_bit_cast(unsigned short, h);
      lo[r][q4*4+j] = __builtin_bit_cast(unsigned short, l);
    }
  }
  __syncthreads();
  #pragma unroll
  for (int it = 0; it < 8; ++it){
    int seg = it*4 + (tid>>6);       // (ks_local 0..3, c 0..7)
    int r = tid & 63;
    int ksl = seg >> 3, c = seg & 7;
    const unsigned short* plane = (c < 4) ? &hi[0][0] : &lo[0][0];
    int kl = ksl*32 + (c & 3)*8;
    u32x4 val = *(const u32x4*)(plane + r*128 + kl);
    int ksg = kt*4 + ksl;
    size_t off = (((size_t)(ksg*8 + c)) * rowstride + (pad + rt*64 + r)) * 16;
    *(u32x4*)(dst + off) = val;
  }
}

// ---------------------------------------------------------------------------
// K1: fused dual-GEMM (q=xWq^T, k=xWk^T) -> per-row dot/nq/nk partials.
// 128 strips x 256 rows, 8 echunks x 128 cols. 512 thr = 8 waves (4M x 2N),
// wave tile 64x64, mfma_f32_32x32x16_f16, 3-term hi/lo split (hh+hl+lh).
// Double-buffered LDS (2 x 65792 B), T3-min pipeline: issue next-K-step
// global_load_lds before the MFMA cluster; one barrier (vmcnt drain) per step.
// Cross-wc (col-half) reduction in LDS before the global partial write.
// ---------------------------------------------------------------------------
__launch_bounds__(512, 2)
__global__ void k1_f16(const unsigned char* __restrict__ xcv,
                       float* __restrict__ dotS, float* __restrict__ nqS,
                       float* __restrict__ nkS)
{
  __shared__ __align__(16) unsigned char lds[2 * BUFSZ];   // 131584 B
  const int tid = threadIdx.x, lane = tid & 63, w = tid >> 6;
  const int wr = w >> 1, wc = w & 1;
  const int bid = blockIdx.x;                 // 1024 blocks
  const int strip = (bid & 7) + ((bid >> 6) << 3);   // same-strip blocks -> same XCD
  const int echunk = (bid >> 3) & 7;
  const int row0 = strip << 8;                // 256 rows/strip
  const int col0 = echunk << 7;               // 128 cols/chunk
  const int l31 = lane & 31, lh = lane >> 5;

  // ---- staging chunk table: 72 chunks (40 x: 8 planes x 5 subs; 16 Wq; 16 Wk)
  // wave w owns chunks w*9 .. w*9+8. goff = absolute byte offset from xcv.
  unsigned goff[9], stride[9]; int loff[9];
  #pragma unroll
  for (int j = 0; j < 9; ++j){
    int cj = w*9 + j;
    if (cj < 40){
      int c = cj / 5, s = cj - c*5;
      int rr0  = (s < 4) ? s*64   : 193;
      int subo = (s < 4) ? s*1024 : 3088;
      goff[j] = ((unsigned)c*XROWS + (unsigned)(row0 + rr0))*16u + (unsigned)lane*16u;
      loff[j] = c*4128 + subo;
      stride[j] = 8u*XROWS*16u;
    } else if (cj < 56){
      int idx = cj - 40, c = idx >> 1, h = idx & 1;
      goff[j] = XCV_BYTES + ((unsigned)c*1024u + (unsigned)(col0 + h*64))*16u + (unsigned)lane*16u;
      loff[j] = 33024 + c*2048 + h*1024;
      stride[j] = 131072u;
    } else {
      int idx = cj - 56, c = idx >> 1, h = idx & 1;
      goff[j] = XCV_BYTES + WCV_BYTES + ((unsigned)c*1024u + (unsigned)(col0 + h*64))*16u + (unsigned)lane*16u;
      loff[j] = 33024 + 16384 + c*2048 + h*1024;
      stride[j] = 131072u;
    }
  }

  // ---- fragment read bases (byte offsets; plane strides: x 4128, W 2048)
  const unsigned bq  = (unsigned)(wr*64 + l31 + 1)*16u + (unsigned)lh*4128u;  // q rows (+1)
  const unsigned bk  = bq - 16u;                                              // k rows
  const unsigned bwq = 33024u + (unsigned)(wc*64 + l31)*16u + (unsigned)lh*2048u;
  const unsigned bwk = bwq + 16384u;

  f32x16 accq[2][2] = {}, acck[2][2] = {};

  // prologue: stage K-step 0 into buffer 0
  #pragma unroll
  for (int j = 0; j < 9; ++j){ gload16(xcv + goff[j], lds + loff[j]); goff[j] += stride[j]; }
  __syncthreads();

  for (int ks = 0; ks < 32; ++ks){
    const unsigned cur = (ks & 1) ? BUFSZ : 0u;
    const unsigned nxt = cur ^ BUFSZ;
    if (ks < 31){
      #pragma unroll
      for (int j = 0; j < 9; ++j){ gload16(xcv + goff[j], lds + loff[j] + nxt); goff[j] += stride[j]; }
    }
    #pragma unroll
    for (int kk = 0; kk < 2; ++kk){
      f16x8 aq[2][2], ak[2][2];   // [mt][hi/lo]
      #pragma unroll
      for (int mt = 0; mt < 2; ++mt)
        #pragma unroll
        for (int hl = 0; hl < 2; ++hl){
          unsigned ao = cur + mt*512u + kk*8256u + hl*16512u;
          aq[mt][hl] = *(const f16x8*)(lds + bq + ao);
          ak[mt][hl] = *(const f16x8*)(lds + bk + ao);
        }
      __builtin_amdgcn_s_setprio(1);
      #pragma unroll
      for (int n = 0; n < 2; ++n){
        unsigned boq = cur + bwq + n*512u + kk*4096u;
        unsigned bok = cur + bwk + n*512u + kk*4096u;
        f16x8 bqh = *(const f16x8*)(lds + boq);
        f16x8 bql = *(const f16x8*)(lds + boq + 8192u);
        f16x8 bkh = *(const f16x8*)(lds + bok);
        f16x8 bkl = *(const f16x8*)(lds + bok + 8192u);
        #pragma unroll
        for (int mt = 0; mt < 2; ++mt){
          accq[mt][n] = __builtin_amdgcn_mfma_f32_32x32x16_f16(aq[mt][0], bqh, accq[mt][n], 0, 0, 0);
          accq[mt][n] = __builtin_amdgcn_mfma_f32_32x32x16_f16(aq[mt][0], bql, accq[mt][n], 0, 0, 0);
          accq[mt][n] = __builtin_amdgcn_mfma_f32_32x32x16_f16(aq[mt][1], bqh, accq[mt][n], 0, 0, 0);
          acck[mt][n] = __builtin_amdgcn_mfma_f32_32x32x16_f16(ak[mt][0], bkh, acck[mt][n], 0, 0, 0);
          acck[mt][n] = __builtin_amdgcn_mfma_f32_32x32x16_f16(ak[mt][0], bkl, acck[mt][n], 0, 0, 0);
          acck[mt][n] = __builtin_amdgcn_mfma_f32_32x32x16_f16(ak[mt][1], bkh, acck[mt][n], 0, 0, 0);
        }
      }
      __builtin_amdgcn_s_setprio(0);
    }
    __syncthreads();   // drains vmcnt(0): next buffer staged, this buffer free
  }

  // ---- fold to per-row scalars; q C-row r <-> k C-row r (rows pre-shifted)
  f32x16 dvv[2], qvv[2], kvv[2];
  #pragma unroll
  for (int mt = 0; mt < 2; ++mt){
    dvv[mt] = accq[mt][0]*acck[mt][0] + accq[mt][1]*acck[mt][1];
    qvv[mt] = accq[mt][0]*accq[mt][0] + accq[mt][1]*accq[mt][1];
    kvv[mt] = acck[mt][0]*acck[mt][0] + acck[mt][1]*acck[mt][1];
  }
  #pragma unroll
  for (int m = 1; m < 32; m <<= 1){
    #pragma unroll
    for (int mt = 0; mt < 2; ++mt)
      #pragma unroll
      for (int r = 0; r < 16; ++r){
        dvv[mt][r] += __shfl_xor(dvv[mt][r], m, 64);
        qvv[mt][r] += __shfl_xor(qvv[mt][r], m, 64);
        kvv[mt][r] += __shfl_xor(kvv[mt][r], m, 64);
      }
  }
  // cross-wc reduce via LDS (wc=1 deposits, wc=0 sums + writes)
  float* scr = (float*)lds;   // 3 planes x 256 floats
  if (l31 == 0 && wc == 1){
    #pragma unroll
    for (int mt = 0; mt < 2; ++mt)
      #pragma unroll
      for (int r = 0; r < 16; ++r){
        int rm = (r & 3) + ((r >> 2) << 3) + (lh << 2);
        int ti = (wr*2 + mt)*32 + rm;
        scr[ti] = dvv[mt][r]; scr[256 + ti] = qvv[mt][r]; scr[512 + ti] = kvv[mt][r];
      }
  }
  __syncthreads();
  if (l31 == 0 && wc == 0){
    #pragma unroll
    for (int mt = 0; mt < 2; ++mt)
      #pragma unroll
      for (int r = 0; r < 16; ++r){
        int rm = (r & 3) + ((r >> 2) << 3) + (lh << 2);
        int ti = (wr*2 + mt)*32 + rm;
        int grow = row0 + wr*64 + mt*32 + rm;
        size_t idx = (size_t)echunk * BL + grow;
        dotS[idx] = dvv[mt][r] + scr[ti];
        nqS[idx]  = qvv[mt][r] + scr[256 + ti];
        nkS[idx]  = kvv[mt][r] + scr[512 + ti];
      }
  }
}

// ---------------------------------------------------------------------------
// K2: combine partials -> p,b; scan -> invmap, lengths, per-batch sums.
// ---------------------------------------------------------------------------
__global__ void k2_scan(const float* __restrict__ dotS, const float* __restrict__ nqS,
                        const float* __restrict__ nkS,
                        float* __restrict__ p_out, float* __restrict__ b_out,
                        float* __restrict__ len_out, int* __restrict__ invmap,
                        float* __restrict__ bat_sums, int* __restrict__ lenI, int nparts)
{
  const int batch = blockIdx.x;
  const int tid   = threadIdx.x;  // 1024
  const int lane  = tid & 63, wv = tid >> 6;
  const int lbase = tid << 3;
  float ps = 0.f; int bc = 0; unsigned bits = 0;
  #pragma unroll
  for (int j = 0; j < 8; ++j){
    const int l = lbase + j;
    const int g = batch * L_ + l;
    float dt = 0.f, nq = 0.f, nk = 0.f;
    for (int e = 0; e < nparts; ++e){
      dt += dotS[(size_t)e*BL + g]; nq += nqS[(size_t)e*BL + g]; nk += nkS[(size_t)e*BL + g];
    }
    float p;
    if (l == 0) p = 1.f;
    else {
      const float dn = fmaxf(sqrtf(nq), 1e-12f) * fmaxf(sqrtf(nk), 1e-12f);
      p = 0.5f * (1.f - dt / dn);
    }
    const int bb = (p >= 0.5f) ? 1 : 0;
    p_out[g] = p;
    b_out[g] = (float)bb;
    ps += p; bc += bb; bits |= (unsigned)bb << j;
  }
  int sc = bc;
  #pragma unroll
  for (int m = 1; m < 64; m <<= 1){
    int t = __shfl_up(sc, m, 64);
    if (lane >= m) sc += t;
  }
  float pss = ps;
  #pragma unroll
  for (int m = 1; m < 64; m <<= 1) pss += __shfl_xor(pss, m, 64);

  __shared__ int wsum[16];
  __shared__ float wps[16];
  if (lane == 63) wsum[wv] = sc;
  if (lane == 0)  wps[wv] = pss;
  __syncthreads();
  if (tid < 16){
    int v = wsum[tid];
    #pragma unroll
    for (int m = 1; m < 16; m <<= 1){
      int t = __shfl_up(v, m, 64);
      if (tid >= m) v += t;
    }
    wsum[tid] = v;
  }
  __syncthreads();
  const int waveoff = (wv == 0) ? 0 : wsum[wv - 1];
  const int total = wsum[15];
  int run = waveoff + sc - bc;
  #pragma unroll
  for (int j = 0; j < 8; ++j){
    if ((bits >> j) & 1u){ invmap[batch * L_ + run] = lbase + j; ++run; }
  }
  if (tid == 0){
    float psum = 0.f;
    #pragma unroll
    for (int i = 0; i < 16; ++i) psum += wps[i];
    bat_sums[batch]     = (float)total;
    bat_sums[4 + batch] = psum;
    lenI[batch]    = total;
    len_out[batch] = (float)total;
  }
}

// ---------------------------------------------------------------------------
// K3: gather-compact, 2048 blocks x 16 slots each (every output written once).
// ---------------------------------------------------------------------------
__global__ void k3_fill(const float* __restrict__ x, const float* __restrict__ p_out,
                        const int* __restrict__ invmap, const int* __restrict__ lenI,
                        const float* __restrict__ bat_sums,
                        float* __restrict__ xdown, float* __restrict__ Pdown,
                        float* __restrict__ loss_out)
{
  const int bid = blockIdx.x, tid = threadIdx.x;
  #pragma unroll 4
  for (int i = 0; i < 16; ++i){
    const int s = bid*16 + i;
    const int batch = s >> 13, j = s & 8191;
    const int len = lenI[batch];
    const int inb = (j < len) ? 1 : 0;
    const int src = inb ? invmap[batch * L_ + j] : 0;
    f32x4 v = {0.f, 0.f, 0.f, 0.f};
    if (inb) v = *(const f32x4*)(x + (((size_t)(batch * L_ + src)) << 10) + (tid << 2));
    *(f32x4*)(xdown + (((size_t)(batch * L_ + j)) << 10) + (tid << 2)) = v;
    if (tid == 0) Pdown[batch * L_ + j] = inb ? p_out[batch * L_ + src] : 0.f;
  }
  if (bid == 0 && tid == 0){
    const float F = (bat_sums[0] + bat_sums[1] + bat_sums[2] + bat_sums[3]) * (1.f / 32768.f);
    const float G = (bat_sums[4] + bat_sums[5] + bat_sums[6] + bat_sums[7]) * (1.f / 32768.f);
    loss_out[0] = 1.2f * (5.f * F * G + (1.f - F) * (1.f - G));  // N=6
  }
}

extern "C" void kernel_launch(void* const* d_in, const int* in_sizes, int n_in,
                              void* d_out, int out_size, void* d_ws, size_t ws_size,
                              hipStream_t stream)
{
  const float* x  = (const float*)d_in[0];
  const float* Wq = (const float*)d_in[1];
  const float* Wk = (const float*)d_in[2];

  float* out      = (float*)d_out;
  float* xdown    = out;                         // (B, L, D)
  float* Pdown    = out + (size_t)BL * D_;       // (B, L)
  float* b_out    = Pdown + BL;                  // (B, L)
  float* p_out    = b_out + BL;                  // (B, L)
  float* len_out  = p_out + BL;                  // (B,)
  float* loss_out = len_out + B_;                // scalar

  unsigned char* xcv = (unsigned char*)d_ws;     // x, Wq, Wk converted planes
  float* dotS     = (float*)(xcv + XCV_BYTES + 2*WCV_BYTES);  // [8][BL]
  float* nqS      = dotS + (size_t)8*BL;
  float* nkS      = nqS + (size_t)8*BL;
  int*   invmap   = (int*)(nkS + (size_t)8*BL);  // [B][L]
  float* bat_sums = (float*)(invmap + BL);       // [8]
  int*   lenI     = (int*)(bat_sums + 8);        // [4]

  hipLaunchKernelGGL(k0_cvt, dim3(544, 8), dim3(256), 0, stream, x, Wq, Wk, xcv);
  hipLaunchKernelGGL(k1_f16, dim3(1024), dim3(512), 0, stream, xcv, dotS, nqS, nkS);
  hipLaunchKernelGGL(k2_scan, dim3(4), dim3(1024), 0, stream,
                     dotS, nqS, nkS, p_out, b_out, len_out, invmap, bat_sums, lenI, 8);
  hipLaunchKernelGGL(k3_fill, dim3(2048), dim3(256), 0, stream,
                     x, p_out, invmap, lenI, bat_sums, xdown, Pdown, loss_out);
}

// Round 4
// 716.112 us; speedup vs baseline: 1.0406x; 1.0406x over previous
//
#include <hip/hip_runtime.h>
#include <stdint.h>
#include <stddef.h>

typedef __attribute__((ext_vector_type(8)))  _Float16 f16x8;
typedef __attribute__((ext_vector_type(16))) float    f32x16;
typedef __attribute__((ext_vector_type(4)))  float    f32x4;
typedef __attribute__((ext_vector_type(4)))  unsigned int u32x4;

#define B_ 4
#define L_ 8192
#define D_ 1024
#define BL 32768
#define XR 32768
#define XCV_BYTES (256u * XR * 16u)      // 134,217,728
#define WCV_BYTES (256u * 1024u * 16u)   //   4,194,304

__device__ __forceinline__ void gload16(const void* g, void* l){
  __builtin_amdgcn_global_load_lds((const __attribute__((address_space(1))) void*)g,
                                   (__attribute__((address_space(3))) void*)l, 16, 0, 0);
}

__device__ __forceinline__ f32x16 MF(f16x8 a, f16x8 b, f32x16 c){
  return __builtin_amdgcn_mfma_f32_32x32x16_f16(a, b, c, 0, 0, 0);
}

// ---------------------------------------------------------------------------
// K0: convert f32 [nrows][1024] -> packed f16 hi/lo planes.
// Plane P = ks*8 + c (ks = 32-k step; c<4: hi of k_local=c*8..c*8+7; c>=4: lo).
// Plane entry = one row (16 B = 8 f16). LDS transpose swizzled (XOR chunk^row)
// so phase-2 column reads are bank-conflict-free.
// ---------------------------------------------------------------------------
__global__ void k0_cvt(const float* __restrict__ x, const float* __restrict__ Wq,
                       const float* __restrict__ Wk, unsigned char* __restrict__ xcv)
{
  __shared__ unsigned short hi[64][128];
  __shared__ unsigned short lo[64][128];
  const int bx = blockIdx.x, kt = blockIdx.y, tid = threadIdx.x;
  const float* src; unsigned char* dst; int rs, rt;
  if (bx < 512){ src = x;  dst = xcv;                         rs = XR;   rt = bx; }
  else if (bx < 528){ src = Wq; dst = xcv + XCV_BYTES;        rs = 1024; rt = bx - 512; }
  else { src = Wk; dst = xcv + XCV_BYTES + WCV_BYTES;         rs = 1024; rt = bx - 528; }

  #pragma unroll
  for (int it = 0; it < 8; ++it){
    int idx = it*256 + tid;          // 2048 f32x4 loads (64 rows x 128 k)
    int r = idx >> 5, q4 = idx & 31;
    f32x4 v = *(const f32x4*)(src + (size_t)(rt*64 + r)*1024 + kt*128 + q4*4);
    int swb = ((q4 >> 1) ^ (r & 15))*8 + (q4 & 1)*4;
    #pragma unroll
    for (int j = 0; j < 4; ++j){
      float f = v[j];
      _Float16 h = (_Float16)f;
      _Float16 l = (_Float16)(f - (float)h);
      hi[r][swb + j] = __builtin_bit_cast(unsigned short, h);
      lo[r][swb + j] = __builtin_bit_cast(unsigned short, l);
    }
  }
  __syncthreads();
  #pragma unroll
  for (int it = 0; it < 8; ++it){
    int seg = it*4 + (tid >> 6);     // (ks_local 0..3, c 0..7)
    int r = tid & 63;
    int ksl = seg >> 3, c = seg & 7;
    const unsigned short* plane = (c < 4) ? &hi[0][0] : &lo[0][0];
    int kl = ksl*32 + (c & 3)*8;
    u32x4 val = *(const u32x4*)(plane + r*128 + ((((kl >> 3) ^ (r & 15))) << 3));
    int P = (kt*4 + ksl)*8 + c;
    *(u32x4*)(dst + ((size_t)P * rs + rt*64 + r) * 16) = val;
  }
}

// ---------------------------------------------------------------------------
// K1: fused dual-GEMM (q=xWq^T, k=xWk^T) -> per-row dot/nq/nk partials.
// q and k SHARE A-fragments (same 256 rows); the q[l]*k[l-1] row shift is done
// at the epilogue through an LDS kbuf. 4 x 32KB half-K-step buffers, 3-ahead
// staging, one raw s_barrier + counted vmcnt(8) per phase (T3/T4), setprio.
// 128 strips x 256 rows, 8 echunks x 128 cols, 8 waves (4M x 2N), 64x64/wave.
// ---------------------------------------------------------------------------
__launch_bounds__(512, 2)
__global__ void k1_f16(const unsigned char* __restrict__ xcv,
                       float* __restrict__ dotP, float* __restrict__ nqP,
                       float* __restrict__ nkP,
                       float* __restrict__ qface, float* __restrict__ kface)
{
  __shared__ __align__(16) unsigned char lds[131072];   // 4 x 32768 staging / kbuf
  const int tid = threadIdx.x, lane = tid & 63, w = tid >> 6;
  const int wr = w >> 1, wc = w & 1, l31 = lane & 31, lh = lane >> 5;
  const int bid = blockIdx.x;
  const int strip = (bid & 7) + ((bid >> 6) << 3);
  const int ec = (bid >> 3) & 7;
  const int row0 = strip << 8, col0 = ec << 7;

  // 32 staging chunks/phase (16 x, 8 wq, 8 wk), 4 per wave.
  unsigned goff[4]; int loff[4]; unsigned d0[4], d1[4];
  #pragma unroll
  for (int j = 0; j < 4; ++j){
    int cj = w*4 + j;
    if (cj < 16){
      int lp = cj >> 2, sub = cj & 3;
      int cg = (lp & 1) + ((lp >> 1) << 2);          // c_global at kk=0
      goff[j] = ((unsigned)cg * XR + (unsigned)(row0 + sub*64 + lane)) * 16u;
      loff[j] = lp*4096 + (sub*64 + lane)*16;
      d0[j] = 2u*XR*16u; d1[j] = 6u*XR*16u;
    } else if (cj < 24){
      int t = cj - 16, lp = t >> 1, hf = t & 1;
      int cg = (lp & 1) + ((lp >> 1) << 2);
      goff[j] = XCV_BYTES + ((unsigned)cg * 1024u + (unsigned)(col0 + hf*64 + lane)) * 16u;
      loff[j] = 16384 + lp*2048 + (hf*64 + lane)*16;
      d0[j] = 32768u; d1[j] = 98304u;
    } else {
      int t = cj - 24, lp = t >> 1, hf = t & 1;
      int cg = (lp & 1) + ((lp >> 1) << 2);
      goff[j] = XCV_BYTES + WCV_BYTES + ((unsigned)cg * 1024u + (unsigned)(col0 + hf*64 + lane)) * 16u;
      loff[j] = 24576 + lp*2048 + (hf*64 + lane)*16;
      d0[j] = 32768u; d1[j] = 98304u;
    }
  }

  #define STAGE(slot) { _Pragma("unroll") \
    for (int j = 0; j < 4; ++j) gload16(xcv + goff[j], lds + (slot) + loff[j]); }
  #define ADV(par) { _Pragma("unroll") \
    for (int j = 0; j < 4; ++j) goff[j] += (par) ? d1[j] : d0[j]; }

  STAGE(0u)      ADV(0)
  STAGE(32768u)  ADV(1)
  STAGE(65536u)  ADV(0)

  const unsigned ab = (unsigned)(lh*4096) + (unsigned)((wr*64 + l31)*16);
  const unsigned bb = 16384u + (unsigned)(lh*2048) + (unsigned)((wc*64 + l31)*16);

  f32x16 accq[2][2] = {}, acck[2][2] = {};

  for (int h = 0; h < 64; ++h){
    if (h < 62)      { asm volatile("s_waitcnt vmcnt(8)" ::: "memory"); }
    else if (h == 62){ asm volatile("s_waitcnt vmcnt(4)" ::: "memory"); }
    else             { asm volatile("s_waitcnt vmcnt(0)" ::: "memory"); }
    __builtin_amdgcn_s_barrier();
    if (h < 61){ unsigned s3 = (unsigned)((h+3) & 3) * 32768u; STAGE(s3) ADV((h+3) & 1) }
    const unsigned cur = (unsigned)(h & 3) * 32768u;
    f16x8 ah[2], al[2];
    ah[0] = *(const f16x8*)(lds + cur + ab);
    ah[1] = *(const f16x8*)(lds + cur + ab + 512u);
    al[0] = *(const f16x8*)(lds + cur + ab + 8192u);
    al[1] = *(const f16x8*)(lds + cur + ab + 8704u);
    #pragma unroll
    for (int n = 0; n < 2; ++n){
      unsigned bo = cur + bb + (unsigned)n*512u;
      f16x8 qh = *(const f16x8*)(lds + bo);
      f16x8 ql = *(const f16x8*)(lds + bo + 4096u);
      f16x8 kh = *(const f16x8*)(lds + bo + 8192u);
      f16x8 kl_ = *(const f16x8*)(lds + bo + 12288u);
      __builtin_amdgcn_s_setprio(1);
      #pragma unroll
      for (int mt = 0; mt < 2; ++mt){
        accq[mt][n] = MF(ah[mt], qh, accq[mt][n]);
        accq[mt][n] = MF(ah[mt], ql, accq[mt][n]);
        accq[mt][n] = MF(al[mt], qh, accq[mt][n]);
        acck[mt][n] = MF(ah[mt], kh, acck[mt][n]);
        acck[mt][n] = MF(ah[mt], kl_, acck[mt][n]);
        acck[mt][n] = MF(al[mt], kh, acck[mt][n]);
      }
      __builtin_amdgcn_s_setprio(0);
    }
  }

  // ---------------- epilogue ----------------
  __syncthreads();
  float* kbuf = (float*)lds;                       // [256][128]
  #pragma unroll
  for (int mt = 0; mt < 2; ++mt)
    #pragma unroll
    for (int r = 0; r < 16; ++r){
      int rm = (r & 3) + ((r >> 2) << 3) + (lh << 2);
      int rl = wr*64 + mt*32 + rm;
      kbuf[rl*128 + wc*64 + l31]      = acck[mt][0][r];
      kbuf[rl*128 + wc*64 + 32 + l31] = acck[mt][1][r];
    }
  __syncthreads();
  f32x16 dvv[2], qvv[2], kvv[2];
  #pragma unroll
  for (int mt = 0; mt < 2; ++mt){
    qvv[mt] = accq[mt][0]*accq[mt][0] + accq[mt][1]*accq[mt][1];
    kvv[mt] = acck[mt][0]*acck[mt][0] + acck[mt][1]*acck[mt][1];
    #pragma unroll
    for (int r = 0; r < 16; ++r){
      int rm = (r & 3) + ((r >> 2) << 3) + (lh << 2);
      int rl = wr*64 + mt*32 + rm;
      int cl = rl - 1; if (cl < 0) cl = 0;         // row r0: garbage, fixed in k2
      float k0v = kbuf[cl*128 + wc*64 + l31];
      float k1v = kbuf[cl*128 + wc*64 + 32 + l31];
      dvv[mt][r] = accq[mt][0][r]*k0v + accq[mt][1][r]*k1v;
    }
  }
  __syncthreads();
  // faces (register-sourced): q first row / k last row e-slices
  if (wr == 0 && lh == 0){
    qface[strip*1024 + ec*128 + wc*64 + l31]      = accq[0][0][0];
    qface[strip*1024 + ec*128 + wc*64 + 32 + l31] = accq[0][1][0];
  }
  if (wr == 3 && lh == 1){
    kface[strip*1024 + ec*128 + wc*64 + l31]      = acck[1][0][15];
    kface[strip*1024 + ec*128 + wc*64 + 32 + l31] = acck[1][1][15];
  }
  // reduce over the 32 cols held by the lane group
  #pragma unroll
  for (int m = 1; m < 32; m <<= 1){
    #pragma unroll
    for (int mt = 0; mt < 2; ++mt)
      #pragma unroll
      for (int r = 0; r < 16; ++r){
        dvv[mt][r] += __shfl_xor(dvv[mt][r], m, 64);
        qvv[mt][r] += __shfl_xor(qvv[mt][r], m, 64);
        kvv[mt][r] += __shfl_xor(kvv[mt][r], m, 64);
      }
  }
  float* scr = (float*)lds;                        // 3 x 256 floats
  if (l31 == 0 && wc == 1){
    #pragma unroll
    for (int mt = 0; mt < 2; ++mt)
      #pragma unroll
      for (int r = 0; r < 16; ++r){
        int rm = (r & 3) + ((r >> 2) << 3) + (lh << 2);
        int ti = (wr*2 + mt)*32 + rm;
        scr[ti] = dvv[mt][r]; scr[256 + ti] = qvv[mt][r]; scr[512 + ti] = kvv[mt][r];
      }
  }
  __syncthreads();
  if (l31 == 0 && wc == 0){
    #pragma unroll
    for (int mt = 0; mt < 2; ++mt)
      #pragma unroll
      for (int r = 0; r < 16; ++r){
        int rm = (r & 3) + ((r >> 2) << 3) + (lh << 2);
        int ti = (wr*2 + mt)*32 + rm;
        size_t idx = (size_t)ec * BL + row0 + wr*64 + mt*32 + rm;
        dotP[idx] = dvv[mt][r] + scr[ti];
        nqP[idx]  = qvv[mt][r] + scr[256 + ti];
        nkP[idx]  = kvv[mt][r] + scr[512 + ti];
      }
  }
}

// ---------------------------------------------------------------------------
// K15: collapse 8 echunk partials -> slice 0 (in place), full-chip parallel.
// ---------------------------------------------------------------------------
__global__ void k15_reduce(float* __restrict__ dotP, float* __restrict__ nqP,
                           float* __restrict__ nkP)
{
  int idx = blockIdx.x*1024 + threadIdx.x;   // 0..98303
  float* base = (idx < 32768) ? dotP : (idx < 65536 ? nqP : nkP);
  int row = idx & 32767;
  float s = 0.f;
  #pragma unroll
  for (int e = 0; e < 8; ++e) s += base[(size_t)e*BL + row];
  base[row] = s;
}

// ---------------------------------------------------------------------------
// K2: finals -> p, b (nk is UNSHIFTED: use nk[l-1]); strip-start dot from
// faces; scan -> invmap, lengths, per-batch sums.
// ---------------------------------------------------------------------------
__global__ void k2_scan(const float* __restrict__ dotF, const float* __restrict__ nqF,
                        const float* __restrict__ nkF,
                        const float* __restrict__ qface, const float* __restrict__ kface,
                        float* __restrict__ p_out, float* __restrict__ b_out,
                        float* __restrict__ len_out, int* __restrict__ invmap,
                        float* __restrict__ bat_sums, int* __restrict__ lenI)
{
  const int batch = blockIdx.x;
  const int tid   = threadIdx.x;  // 1024
  const int lane  = tid & 63, wv = tid >> 6;
  const int lb    = tid << 3;
  const int g0    = batch * L_ + lb;

  float dta[8], nqa[8], nka[8];
  *(f32x4*)(dta)   = *(const f32x4*)(dotF + g0); *(f32x4*)(dta+4) = *(const f32x4*)(dotF + g0 + 4);
  *(f32x4*)(nqa)   = *(const f32x4*)(nqF + g0);  *(f32x4*)(nqa+4) = *(const f32x4*)(nqF + g0 + 4);
  *(f32x4*)(nka)   = *(const f32x4*)(nkF + g0);  *(f32x4*)(nka+4) = *(const f32x4*)(nkF + g0 + 4);
  float nkp = (lb > 0) ? nkF[g0 - 1] : 0.f;

  float ps = 0.f; int bc = 0; unsigned bits = 0;
  #pragma unroll
  for (int j = 0; j < 8; ++j){
    const int l = lb + j;
    const int g = batch * L_ + l;
    float p;
    if (l == 0) p = 1.f;
    else {
      float dt = dta[j];
      if ((l & 255) == 0){
        int s = g >> 8;
        const f32x4* qf = (const f32x4*)(qface + (size_t)s*1024);
        const f32x4* kf = (const f32x4*)(kface + (size_t)(s-1)*1024);
        f32x4 a4 = {0.f,0.f,0.f,0.f};
        for (int i = 0; i < 256; ++i) a4 += qf[i]*kf[i];
        dt = a4[0] + a4[1] + a4[2] + a4[3];
      }
      float nkprev = j ? nka[j-1] : nkp;
      float dn = fmaxf(sqrtf(nqa[j]), 1e-12f) * fmaxf(sqrtf(nkprev), 1e-12f);
      p = 0.5f * (1.f - dt/dn);
    }
    const int bb = (p >= 0.5f) ? 1 : 0;
    p_out[g] = p;
    b_out[g] = (float)bb;
    ps += p; bc += bb; bits |= (unsigned)bb << j;
  }
  int sc = bc;
  #pragma unroll
  for (int m = 1; m < 64; m <<= 1){
    int t = __shfl_up(sc, m, 64);
    if (lane >= m) sc += t;
  }
  float pss = ps;
  #pragma unroll
  for (int m = 1; m < 64; m <<= 1) pss += __shfl_xor(pss, m, 64);

  __shared__ int wsum[16];
  __shared__ float wps[16];
  if (lane == 63) wsum[wv] = sc;
  if (lane == 0)  wps[wv] = pss;
  __syncthreads();
  if (tid < 16){
    int v = wsum[tid];
    #pragma unroll
    for (int m = 1; m < 16; m <<= 1){
      int t = __shfl_up(v, m, 64);
      if (tid >= m) v += t;
    }
    wsum[tid] = v;
  }
  __syncthreads();
  const int waveoff = (wv == 0) ? 0 : wsum[wv - 1];
  const int total = wsum[15];
  int run = waveoff + sc - bc;
  #pragma unroll
  for (int j = 0; j < 8; ++j){
    if ((bits >> j) & 1u){ invmap[batch * L_ + run] = lb + j; ++run; }
  }
  if (tid == 0){
    float psum = 0.f;
    #pragma unroll
    for (int i = 0; i < 16; ++i) psum += wps[i];
    bat_sums[batch]     = (float)total;
    bat_sums[4 + batch] = psum;
    lenI[batch]    = total;
    len_out[batch] = (float)total;
  }
}

// ---------------------------------------------------------------------------
// K3: gather-compact, 2048 blocks x 16 slots (every output written once).
// ---------------------------------------------------------------------------
__global__ void k3_fill(const float* __restrict__ x, const float* __restrict__ p_out,
                        const int* __restrict__ invmap, const int* __restrict__ lenI,
                        const float* __restrict__ bat_sums,
                        float* __restrict__ xdown, float* __restrict__ Pdown,
                        float* __restrict__ loss_out)
{
  const int bid = blockIdx.x, tid = threadIdx.x;
  #pragma unroll 4
  for (int i = 0; i < 16; ++i){
    const int s = bid*16 + i;
    const int batch = s >> 13, j = s & 8191;
    const int len = lenI[batch];
    const int inb = (j < len) ? 1 : 0;
    const int src = inb ? invmap[batch * L_ + j] : 0;
    f32x4 v = {0.f, 0.f, 0.f, 0.f};
    if (inb) v = *(const f32x4*)(x + (((size_t)(batch * L_ + src)) << 10) + (tid << 2));
    *(f32x4*)(xdown + (((size_t)(batch * L_ + j)) << 10) + (tid << 2)) = v;
    if (tid == 0) Pdown[batch * L_ + j] = inb ? p_out[batch * L_ + src] : 0.f;
  }
  if (bid == 0 && tid == 0){
    const float F = (bat_sums[0] + bat_sums[1] + bat_sums[2] + bat_sums[3]) * (1.f / 32768.f);
    const float G = (bat_sums[4] + bat_sums[5] + bat_sums[6] + bat_sums[7]) * (1.f / 32768.f);
    loss_out[0] = 1.2f * (5.f * F * G + (1.f - F) * (1.f - G));  // N=6
  }
}

extern "C" void kernel_launch(void* const* d_in, const int* in_sizes, int n_in,
                              void* d_out, int out_size, void* d_ws, size_t ws_size,
                              hipStream_t stream)
{
  const float* x  = (const float*)d_in[0];
  const float* Wq = (const float*)d_in[1];
  const float* Wk = (const float*)d_in[2];

  float* out      = (float*)d_out;
  float* xdown    = out;                         // (B, L, D)
  float* Pdown    = out + (size_t)BL * D_;       // (B, L)
  float* b_out    = Pdown + BL;                  // (B, L)
  float* p_out    = b_out + BL;                  // (B, L)
  float* len_out  = p_out + BL;                  // (B,)
  float* loss_out = len_out + B_;                // scalar

  // faces live in the xdown region (k3 overwrites it after k2 consumed them)
  float* qface = xdown + (size_t)4*1024*1024;
  float* kface = qface + 131072;

  unsigned char* xcv = (unsigned char*)d_ws;     // x, Wq, Wk converted planes
  float* dotP     = (float*)(xcv + XCV_BYTES + 2*WCV_BYTES);  // [8][BL] (slice0 = final)
  float* nqP      = dotP + (size_t)8*BL;
  float* nkP      = nqP + (size_t)8*BL;
  int*   invmap   = (int*)(nkP + (size_t)8*BL);  // [B][L]
  float* bat_sums = (float*)(invmap + BL);       // [8]
  int*   lenI     = (int*)(bat_sums + 8);        // [4]

  hipLaunchKernelGGL(k0_cvt, dim3(544, 8), dim3(256), 0, stream, x, Wq, Wk, xcv);
  hipLaunchKernelGGL(k1_f16, dim3(1024), dim3(512), 0, stream,
                     xcv, dotP, nqP, nkP, qface, kface);
  hipLaunchKernelGGL(k15_reduce, dim3(96), dim3(1024), 0, stream, dotP, nqP, nkP);
  hipLaunchKernelGGL(k2_scan, dim3(4), dim3(1024), 0, stream,
                     dotP, nqP, nkP, qface, kface,
                     p_out, b_out, len_out, invmap, bat_sums, lenI);
  hipLaunchKernelGGL(k3_fill, dim3(2048), dim3(256), 0, stream,
                     x, p_out, invmap, lenI, bat_sums, xdown, Pdown, loss_out);
}

// Round 5
// 666.264 us; speedup vs baseline: 1.1184x; 1.0748x over previous
//
#include <hip/hip_runtime.h>
#include <stdint.h>
#include <stddef.h>

typedef __attribute__((ext_vector_type(8)))  _Float16 f16x8;
typedef __attribute__((ext_vector_type(16))) float    f32x16;
typedef __attribute__((ext_vector_type(4)))  float    f32x4;
typedef __attribute__((ext_vector_type(4)))  unsigned int u32x4;

#define B_ 4
#define L_ 8192
#define D_ 1024
#define BL 32768
#define XR 32768
#define XCV_BYTES (256u * XR * 16u)      // 134,217,728
#define WCV_BYTES (256u * 1024u * 16u)   //   4,194,304

__device__ __forceinline__ void gload16(const void* g, void* l){
  __builtin_amdgcn_global_load_lds((const __attribute__((address_space(1))) void*)g,
                                   (__attribute__((address_space(3))) void*)l, 16, 0, 0);
}

__device__ __forceinline__ f32x16 MF(f16x8 a, f16x8 b, f32x16 c){
  return __builtin_amdgcn_mfma_f32_32x32x16_f16(a, b, c, 0, 0, 0);
}

// ---------------------------------------------------------------------------
// K0: convert f32 [nrows][1024] -> packed f16 hi/lo planes (unchanged).
// ---------------------------------------------------------------------------
__global__ void k0_cvt(const float* __restrict__ x, const float* __restrict__ Wq,
                       const float* __restrict__ Wk, unsigned char* __restrict__ xcv)
{
  __shared__ unsigned short hi[64][128];
  __shared__ unsigned short lo[64][128];
  const int bx = blockIdx.x, kt = blockIdx.y, tid = threadIdx.x;
  const float* src; unsigned char* dst; int rs, rt;
  if (bx < 512){ src = x;  dst = xcv;                         rs = XR;   rt = bx; }
  else if (bx < 528){ src = Wq; dst = xcv + XCV_BYTES;        rs = 1024; rt = bx - 512; }
  else { src = Wk; dst = xcv + XCV_BYTES + WCV_BYTES;         rs = 1024; rt = bx - 528; }

  #pragma unroll
  for (int it = 0; it < 8; ++it){
    int idx = it*256 + tid;
    int r = idx >> 5, q4 = idx & 31;
    f32x4 v = *(const f32x4*)(src + (size_t)(rt*64 + r)*1024 + kt*128 + q4*4);
    int swb = ((q4 >> 1) ^ (r & 15))*8 + (q4 & 1)*4;
    #pragma unroll
    for (int j = 0; j < 4; ++j){
      float f = v[j];
      _Float16 h = (_Float16)f;
      _Float16 l = (_Float16)(f - (float)h);
      hi[r][swb + j] = __builtin_bit_cast(unsigned short, h);
      lo[r][swb + j] = __builtin_bit_cast(unsigned short, l);
    }
  }
  __syncthreads();
  #pragma unroll
  for (int it = 0; it < 8; ++it){
    int seg = it*4 + (tid >> 6);
    int r = tid & 63;
    int ksl = seg >> 3, c = seg & 7;
    const unsigned short* plane = (c < 4) ? &hi[0][0] : &lo[0][0];
    int kl = ksl*32 + (c & 3)*8;
    u32x4 val = *(const u32x4*)(plane + r*128 + ((((kl >> 3) ^ (r & 15))) << 3));
    int P = (kt*4 + ksl)*8 + c;
    *(u32x4*)(dst + ((size_t)P * rs + rt*64 + r) * 16) = val;
  }
}

// ---------------------------------------------------------------------------
// K1: fused dual-GEMM with q/k WAVE ROLE SPLIT.
// wc=0 waves: q = x Wq^T only; wc=1 waves: k = x Wk^T only. Each wave covers
// 64 rows x 128 cols (n=0..3), so per phase: 12 ds_read_b128 vs 24 MFMA ->
// matrix-pipe-bound. Staging/pipeline identical to round 4 (4 x 32KB slots,
// 3-ahead, counted vmcnt(8)). Epilogue: k-waves deposit acck into LDS kbuf
// [256][128] f32 (reuses staging LDS exactly), q-waves read row-shifted.
// ---------------------------------------------------------------------------
__launch_bounds__(512, 2)
__global__ void k1_f16(const unsigned char* __restrict__ xcv,
                       float* __restrict__ dotP, float* __restrict__ nqP,
                       float* __restrict__ nkP,
                       float* __restrict__ qface, float* __restrict__ kface)
{
  __shared__ __align__(16) unsigned char lds[131072];
  const int tid = threadIdx.x, lane = tid & 63, w = tid >> 6;
  const int wr = w >> 1, wc = w & 1, l31 = lane & 31, lh = lane >> 5;
  const int bid = blockIdx.x;
  const int strip = (bid & 7) + ((bid >> 6) << 3);
  const int ec = (bid >> 3) & 7;
  const int row0 = strip << 8, col0 = ec << 7;

  unsigned goff[4]; int loff[4]; unsigned d0[4], d1[4];
  #pragma unroll
  for (int j = 0; j < 4; ++j){
    int cj = w*4 + j;
    if (cj < 16){
      int lp = cj >> 2, sub = cj & 3;
      int cg = (lp & 1) + ((lp >> 1) << 2);
      goff[j] = ((unsigned)cg * XR + (unsigned)(row0 + sub*64 + lane)) * 16u;
      loff[j] = lp*4096 + (sub*64 + lane)*16;
      d0[j] = 2u*XR*16u; d1[j] = 6u*XR*16u;
    } else if (cj < 24){
      int t = cj - 16, lp = t >> 1, hf = t & 1;
      int cg = (lp & 1) + ((lp >> 1) << 2);
      goff[j] = XCV_BYTES + ((unsigned)cg * 1024u + (unsigned)(col0 + hf*64 + lane)) * 16u;
      loff[j] = 16384 + lp*2048 + (hf*64 + lane)*16;
      d0[j] = 32768u; d1[j] = 98304u;
    } else {
      int t = cj - 24, lp = t >> 1, hf = t & 1;
      int cg = (lp & 1) + ((lp >> 1) << 2);
      goff[j] = XCV_BYTES + WCV_BYTES + ((unsigned)cg * 1024u + (unsigned)(col0 + hf*64 + lane)) * 16u;
      loff[j] = 24576 + lp*2048 + (hf*64 + lane)*16;
      d0[j] = 32768u; d1[j] = 98304u;
    }
  }

  #define STAGE(slot) { _Pragma("unroll") \
    for (int j = 0; j < 4; ++j) gload16(xcv + goff[j], lds + (slot) + loff[j]); }
  #define ADV(par) { _Pragma("unroll") \
    for (int j = 0; j < 4; ++j) goff[j] += (par) ? d1[j] : d0[j]; }

  STAGE(0u)      ADV(0)
  STAGE(32768u)  ADV(1)
  STAGE(65536u)  ADV(0)

  // A: row = wr*64 + mt*32 + l31, k-half = lh. B: col = n*32 + l31, own W.
  const unsigned ab  = (unsigned)(lh*4096) + (unsigned)((wr*64 + l31)*16);
  const unsigned bb0 = 16384u + (unsigned)(wc*8192) + (unsigned)(lh*2048) + (unsigned)(l31*16);

  f32x16 acc[2][4] = {};

  for (int h = 0; h < 64; ++h){
    if (h < 62)      { asm volatile("s_waitcnt vmcnt(8)" ::: "memory"); }
    else if (h == 62){ asm volatile("s_waitcnt vmcnt(4)" ::: "memory"); }
    else             { asm volatile("s_waitcnt vmcnt(0)" ::: "memory"); }
    __builtin_amdgcn_s_barrier();
    if (h < 61){ unsigned s3 = (unsigned)((h+3) & 3) * 32768u; STAGE(s3) ADV((h+3) & 1) }
    const unsigned cur = (unsigned)(h & 3) * 32768u;
    f16x8 ah[2], al[2];
    ah[0] = *(const f16x8*)(lds + cur + ab);
    ah[1] = *(const f16x8*)(lds + cur + ab + 512u);
    al[0] = *(const f16x8*)(lds + cur + ab + 8192u);
    al[1] = *(const f16x8*)(lds + cur + ab + 8704u);
    #pragma unroll
    for (int n = 0; n < 4; ++n){
      unsigned bo = cur + bb0 + (unsigned)n*512u;
      f16x8 bh = *(const f16x8*)(lds + bo);
      f16x8 bl = *(const f16x8*)(lds + bo + 4096u);
      __builtin_amdgcn_s_setprio(1);
      #pragma unroll
      for (int mt = 0; mt < 2; ++mt){
        acc[mt][n] = MF(ah[mt], bh, acc[mt][n]);
        acc[mt][n] = MF(ah[mt], bl, acc[mt][n]);
        acc[mt][n] = MF(al[mt], bh, acc[mt][n]);
      }
      __builtin_amdgcn_s_setprio(0);
    }
  }

  // ---------------- epilogue ----------------
  __syncthreads();
  float* kbuf = (float*)lds;                       // [256][128] f32 = 131072 B
  if (wc == 1){
    #pragma unroll
    for (int mt = 0; mt < 2; ++mt)
      #pragma unroll
      for (int n = 0; n < 4; ++n)
        #pragma unroll
        for (int r = 0; r < 16; ++r){
          int rm = (r & 3) + ((r >> 2) << 3) + (lh << 2);
          int rl = wr*64 + mt*32 + rm;
          kbuf[rl*128 + n*32 + l31] = acc[mt][n][r];
        }
  }
  __syncthreads();

  // faces from registers (q first row / k last row of the block)
  if (wc == 0 && wr == 0 && lh == 0){
    #pragma unroll
    for (int n = 0; n < 4; ++n)
      qface[strip*1024 + ec*128 + n*32 + l31] = acc[0][n][0];     // row 0
  }
  if (wc == 1 && wr == 3 && lh == 1){
    #pragma unroll
    for (int n = 0; n < 4; ++n)
      kface[strip*1024 + ec*128 + n*32 + l31] = acc[1][n][15];    // row 255
  }

  f32x16 dv[2], sv[2];   // q-waves: dv=dot, sv=|q|^2 ; k-waves: sv=|k|^2
  #pragma unroll
  for (int mt = 0; mt < 2; ++mt){
    sv[mt] = acc[mt][0]*acc[mt][0] + acc[mt][1]*acc[mt][1]
           + acc[mt][2]*acc[mt][2] + acc[mt][3]*acc[mt][3];
    if (wc == 0){
      #pragma unroll
      for (int r = 0; r < 16; ++r){
        int rm = (r & 3) + ((r >> 2) << 3) + (lh << 2);
        int rl = wr*64 + mt*32 + rm;
        int cl = rl - 1; if (cl < 0) cl = 0;       // row0: fixed in k2 via faces
        float s = 0.f;
        #pragma unroll
        for (int n = 0; n < 4; ++n)
          s += acc[mt][n][r] * kbuf[cl*128 + n*32 + l31];
        dv[mt][r] = s;
      }
    }
  }
  #pragma unroll
  for (int m = 1; m < 32; m <<= 1){
    #pragma unroll
    for (int mt = 0; mt < 2; ++mt)
      #pragma unroll
      for (int r = 0; r < 16; ++r){
        sv[mt][r] += __shfl_xor(sv[mt][r], m, 64);
        if (wc == 0) dv[mt][r] += __shfl_xor(dv[mt][r], m, 64);
      }
  }
  if (l31 == 0){
    #pragma unroll
    for (int mt = 0; mt < 2; ++mt)
      #pragma unroll
      for (int r = 0; r < 16; ++r){
        int rm = (r & 3) + ((r >> 2) << 3) + (lh << 2);
        size_t idx = (size_t)ec * BL + row0 + wr*64 + mt*32 + rm;
        if (wc == 0){ dotP[idx] = dv[mt][r]; nqP[idx] = sv[mt][r]; }
        else        { nkP[idx] = sv[mt][r]; }
      }
  }
}

// ---------------------------------------------------------------------------
// K15: (a) collapse 8 echunk partials -> slice 0; (b) face-dots: facedot[s] =
// qface[s] . kface[s-1], one wave per strip s.
// ---------------------------------------------------------------------------
__global__ void k15_reduce(float* __restrict__ dotP, float* __restrict__ nqP,
                           float* __restrict__ nkP,
                           const float* __restrict__ qface,
                           const float* __restrict__ kface,
                           float* __restrict__ facedot)
{
  const int b = blockIdx.x, tid = threadIdx.x;
  if (b < 96){
    int idx = b*1024 + tid;                 // 0..98303
    float* base = (idx < 32768) ? dotP : (idx < 65536 ? nqP : nkP);
    int row = idx & 32767;
    float s = 0.f;
    #pragma unroll
    for (int e = 0; e < 8; ++e) s += base[(size_t)e*BL + row];
    base[row] = s;
  } else {
    const int lane = tid & 63, wv = tid >> 6;
    const int s = (b - 96)*16 + wv;         // strip 0..127
    float acc4 = 0.f;
    if (s > 0){
      const f32x4* qf = (const f32x4*)(qface + (size_t)s*1024);
      const f32x4* kf = (const f32x4*)(kface + (size_t)(s-1)*1024);
      f32x4 a = {0.f,0.f,0.f,0.f};
      #pragma unroll
      for (int i = 0; i < 4; ++i) a += qf[lane*4 + i] * kf[lane*4 + i];
      acc4 = a[0] + a[1] + a[2] + a[3];
    }
    #pragma unroll
    for (int m = 1; m < 64; m <<= 1) acc4 += __shfl_xor(acc4, m, 64);
    if (lane == 0) facedot[s] = acc4;
  }
}

// ---------------------------------------------------------------------------
// K2: finals -> p, b (nk UNSHIFTED: use nk[l-1]); strip-start dot from
// facedot; scan -> invmap, lengths, per-batch sums.
// ---------------------------------------------------------------------------
__global__ void k2_scan(const float* __restrict__ dotF, const float* __restrict__ nqF,
                        const float* __restrict__ nkF, const float* __restrict__ facedot,
                        float* __restrict__ p_out, float* __restrict__ b_out,
                        float* __restrict__ len_out, int* __restrict__ invmap,
                        float* __restrict__ bat_sums, int* __restrict__ lenI)
{
  const int batch = blockIdx.x;
  const int tid   = threadIdx.x;  // 1024
  const int lane  = tid & 63, wv = tid >> 6;
  const int lb    = tid << 3;
  const int g0    = batch * L_ + lb;

  float dta[8], nqa[8], nka[8];
  *(f32x4*)(dta)   = *(const f32x4*)(dotF + g0); *(f32x4*)(dta+4) = *(const f32x4*)(dotF + g0 + 4);
  *(f32x4*)(nqa)   = *(const f32x4*)(nqF + g0);  *(f32x4*)(nqa+4) = *(const f32x4*)(nqF + g0 + 4);
  *(f32x4*)(nka)   = *(const f32x4*)(nkF + g0);  *(f32x4*)(nka+4) = *(const f32x4*)(nkF + g0 + 4);
  float nkp = (lb > 0) ? nkF[g0 - 1] : 0.f;

  float ps = 0.f; int bc = 0; unsigned bits = 0;
  #pragma unroll
  for (int j = 0; j < 8; ++j){
    const int l = lb + j;
    const int g = batch * L_ + l;
    float p;
    if (l == 0) p = 1.f;
    else {
      float dt = ((l & 255) == 0) ? facedot[g >> 8] : dta[j];
      float nkprev = j ? nka[j-1] : nkp;
      float dn = fmaxf(sqrtf(nqa[j]), 1e-12f) * fmaxf(sqrtf(nkprev), 1e-12f);
      p = 0.5f * (1.f - dt/dn);
    }
    const int bb = (p >= 0.5f) ? 1 : 0;
    p_out[g] = p;
    b_out[g] = (float)bb;
    ps += p; bc += bb; bits |= (unsigned)bb << j;
  }
  int sc = bc;
  #pragma unroll
  for (int m = 1; m < 64; m <<= 1){
    int t = __shfl_up(sc, m, 64);
    if (lane >= m) sc += t;
  }
  float pss = ps;
  #pragma unroll
  for (int m = 1; m < 64; m <<= 1) pss += __shfl_xor(pss, m, 64);

  __shared__ int wsum[16];
  __shared__ float wps[16];
  if (lane == 63) wsum[wv] = sc;
  if (lane == 0)  wps[wv] = pss;
  __syncthreads();
  if (tid < 16){
    int v = wsum[tid];
    #pragma unroll
    for (int m = 1; m < 16; m <<= 1){
      int t = __shfl_up(v, m, 64);
      if (tid >= m) v += t;
    }
    wsum[tid] = v;
  }
  __syncthreads();
  const int waveoff = (wv == 0) ? 0 : wsum[wv - 1];
  const int total = wsum[15];
  int run = waveoff + sc - bc;
  #pragma unroll
  for (int j = 0; j < 8; ++j){
    if ((bits >> j) & 1u){ invmap[batch * L_ + run] = lb + j; ++run; }
  }
  if (tid == 0){
    float psum = 0.f;
    #pragma unroll
    for (int i = 0; i < 16; ++i) psum += wps[i];
    bat_sums[batch]     = (float)total;
    bat_sums[4 + batch] = psum;
    lenI[batch]    = total;
    len_out[batch] = (float)total;
  }
}

// ---------------------------------------------------------------------------
// K3: gather-compact, 2048 blocks x 16 slots (every output written once).
// ---------------------------------------------------------------------------
__global__ void k3_fill(const float* __restrict__ x, const float* __restrict__ p_out,
                        const int* __restrict__ invmap, const int* __restrict__ lenI,
                        const float* __restrict__ bat_sums,
                        float* __restrict__ xdown, float* __restrict__ Pdown,
                        float* __restrict__ loss_out)
{
  const int bid = blockIdx.x, tid = threadIdx.x;
  #pragma unroll 4
  for (int i = 0; i < 16; ++i){
    const int s = bid*16 + i;
    const int batch = s >> 13, j = s & 8191;
    const int len = lenI[batch];
    const int inb = (j < len) ? 1 : 0;
    const int src = inb ? invmap[batch * L_ + j] : 0;
    f32x4 v = {0.f, 0.f, 0.f, 0.f};
    if (inb) v = *(const f32x4*)(x + (((size_t)(batch * L_ + src)) << 10) + (tid << 2));
    *(f32x4*)(xdown + (((size_t)(batch * L_ + j)) << 10) + (tid << 2)) = v;
    if (tid == 0) Pdown[batch * L_ + j] = inb ? p_out[batch * L_ + src] : 0.f;
  }
  if (bid == 0 && tid == 0){
    const float F = (bat_sums[0] + bat_sums[1] + bat_sums[2] + bat_sums[3]) * (1.f / 32768.f);
    const float G = (bat_sums[4] + bat_sums[5] + bat_sums[6] + bat_sums[7]) * (1.f / 32768.f);
    loss_out[0] = 1.2f * (5.f * F * G + (1.f - F) * (1.f - G));  // N=6
  }
}

extern "C" void kernel_launch(void* const* d_in, const int* in_sizes, int n_in,
                              void* d_out, int out_size, void* d_ws, size_t ws_size,
                              hipStream_t stream)
{
  const float* x  = (const float*)d_in[0];
  const float* Wq = (const float*)d_in[1];
  const float* Wk = (const float*)d_in[2];

  float* out      = (float*)d_out;
  float* xdown    = out;                         // (B, L, D)
  float* Pdown    = out + (size_t)BL * D_;       // (B, L)
  float* b_out    = Pdown + BL;                  // (B, L)
  float* p_out    = b_out + BL;                  // (B, L)
  float* len_out  = p_out + BL;                  // (B,)
  float* loss_out = len_out + B_;                // scalar

  // faces live in the xdown region (k3 overwrites it after k2 consumed them)
  float* qface = xdown + (size_t)4*1024*1024;
  float* kface = qface + 131072;

  unsigned char* xcv = (unsigned char*)d_ws;     // x, Wq, Wk converted planes
  float* dotP     = (float*)(xcv + XCV_BYTES + 2*WCV_BYTES);  // [8][BL] (slice0 = final)
  float* nqP      = dotP + (size_t)8*BL;
  float* nkP      = nqP + (size_t)8*BL;
  int*   invmap   = (int*)(nkP + (size_t)8*BL);  // [B][L]
  float* bat_sums = (float*)(invmap + BL);       // [8]
  int*   lenI     = (int*)(bat_sums + 8);        // [4]
  float* facedot  = (float*)(lenI + 4);          // [128]

  hipLaunchKernelGGL(k0_cvt, dim3(544, 8), dim3(256), 0, stream, x, Wq, Wk, xcv);
  hipLaunchKernelGGL(k1_f16, dim3(1024), dim3(512), 0, stream,
                     xcv, dotP, nqP, nkP, qface, kface);
  hipLaunchKernelGGL(k15_reduce, dim3(104), dim3(1024), 0, stream,
                     dotP, nqP, nkP, qface, kface, facedot);
  hipLaunchKernelGGL(k2_scan, dim3(4), dim3(1024), 0, stream,
                     dotP, nqP, nkP, facedot,
                     p_out, b_out, len_out, invmap, bat_sums, lenI);
  hipLaunchKernelGGL(k3_fill, dim3(2048), dim3(256), 0, stream,
                     x, p_out, invmap, lenI, bat_sums, xdown, Pdown, loss_out);
}